// Round 7
// baseline (174.762 us; speedup 1.0000x reference)
//
#include <hip/hip_runtime.h>
#include <math.h>

#define T_LEN 256
#define HID 10

typedef float v2f __attribute__((ext_vector_type(2)));

__device__ __forceinline__ v2f mk2(float a, float b) { v2f r; r.x = a; r.y = b; return r; }
__device__ __forceinline__ v2f splat2(float a) { return mk2(a, a); }

// setup-only accurate softplus
__device__ __forceinline__ float softplus_f(float x) {
    return fmaxf(x, 0.0f) + log1pf(expf(-fabsf(x)));
}
__device__ __forceinline__ float samp(const float* mu, const float* rho,
                                      const float* eps, int i) {
    return mu[i] + softplus_f(rho[i]) * eps[i];
}

#define NLOG2E (-1.442695040888963f)   // i,f,o gate-input pre-scale
#define P2LOG2E (2.885390081777927f)   // g gate-input pre-scale (and c-state scale)

// gate activations on PRE-SCALED inputs (input scale folded into weights):
// sigmoid: a = -log2e*x  ->  1/(1+exp2(a))
__device__ __forceinline__ float sig_pre(float a) {
    return __builtin_amdgcn_rcpf(1.0f + __builtin_amdgcn_exp2f(a));
}
// g-gate tanh with OUTPUT scaled by P2LOG2E (so c is kept as cs = P2LOG2E*c):
// a = 2log2e*x -> P2LOG2E*(1 - 2/(exp2(a)+1)) = fma(-2L, rcp(e+1), L)
__device__ __forceinline__ float g_act_scaled(float a) {
    return fmaf(-2.0f * P2LOG2E,
                __builtin_amdgcn_rcpf(__builtin_amdgcn_exp2f(a) + 1.0f),
                P2LOG2E);
}
// tanh(c) from the pre-scaled state cs = 2log2e*c: 1 - 2/(exp2(cs)+1)
__device__ __forceinline__ float tanh_from_cs(float cs) {
    return fmaf(-2.0f, __builtin_amdgcn_rcpf(__builtin_amdgcn_exp2f(cs) + 1.0f), 1.0f);
}

// DPP row rotate-right by R within each 16-lane row (VALU pipe, no DS):
// dst lane i = src lane (i - R) mod 16.  (convention verified in R4/R6)
#define ROTF(hi, R) __int_as_float(__builtin_amdgcn_mov_dpp((hi), 0x120 + (R), 0xF, 0xF, true))

struct Wreg {
    // wsel01[r] = whh row ((k - r) & 15), col pair {i,f} of this lane's unit k,
    // input-pre-scaled (zero for pad rows >= HID and pad lanes k >= HID)
    v2f wsel01[16], wsel23[16];
    v2f wih01, wih23, b01, b23;   // input-pre-scaled
};

// One LSTM step for TWO elements (A,B), hand-interleaved so every other
// instruction is from the independent stream. Single accumulator chain per
// gate pair (17 serial pk-FMAs, well under the issue time of the pair).
__device__ __forceinline__ void lstm_step2(const Wreg& w, float xA, float xB,
                                           float& hkA, float& hkB,
                                           float& csA, float& csB)
{
    const int hiA = __float_as_int(hkA);
    const int hiB = __float_as_int(hkB);
    v2f a01A = __builtin_elementwise_fma(splat2(xA), w.wih01, w.b01);
    v2f a01B = __builtin_elementwise_fma(splat2(xB), w.wih01, w.b01);
    v2f a23A = __builtin_elementwise_fma(splat2(xA), w.wih23, w.b23);
    v2f a23B = __builtin_elementwise_fma(splat2(xB), w.wih23, w.b23);
    a01A = __builtin_elementwise_fma(splat2(hkA), w.wsel01[0], a01A);
    a01B = __builtin_elementwise_fma(splat2(hkB), w.wsel01[0], a01B);
    a23A = __builtin_elementwise_fma(splat2(hkA), w.wsel23[0], a23A);
    a23B = __builtin_elementwise_fma(splat2(hkB), w.wsel23[0], a23B);
#define RR(R)                                                              \
    {                                                                      \
        v2f hrA = splat2(ROTF(hiA, R));                                    \
        v2f hrB = splat2(ROTF(hiB, R));                                    \
        a01A = __builtin_elementwise_fma(hrA, w.wsel01[R], a01A);          \
        a01B = __builtin_elementwise_fma(hrB, w.wsel01[R], a01B);          \
        a23A = __builtin_elementwise_fma(hrA, w.wsel23[R], a23A);          \
        a23B = __builtin_elementwise_fma(hrB, w.wsel23[R], a23B);          \
    }
    RR(1)  RR(2)  RR(3)  RR(4)  RR(5)  RR(6)  RR(7)  RR(8)
    RR(9)  RR(10) RR(11) RR(12) RR(13) RR(14) RR(15)
#undef RR
    float igA = sig_pre(a01A.x);
    float igB = sig_pre(a01B.x);
    float fgA = sig_pre(a01A.y);
    float fgB = sig_pre(a01B.y);
    float ggA = g_act_scaled(a23A.x);     // output pre-scaled by P2LOG2E
    float ggB = g_act_scaled(a23B.x);
    float ogA = sig_pre(a23A.y);
    float ogB = sig_pre(a23B.y);
    csA = fmaf(fgA, csA, igA * ggA);      // cs = P2LOG2E * c
    csB = fmaf(fgB, csB, igB * ggB);
    float thA = tanh_from_cs(csA);
    float thB = tanh_from_cs(csB);
    hkA = ogA * thA;
    hkB = ogB * thB;
}

// One wave per block; TWO elements per 16-lane row (weights shared) -> 8
// elements/wave, 8192/8 = 1024 single-wave blocks = exactly 1 wave per SIMD.
// No DS ops in the recurrence; A/B streams hand-interleaved to keep the
// single-wave issue pipe full.
__global__ __launch_bounds__(64) void bayes_lstm_kernel(
    const float* __restrict__ x,
    const float* __restrict__ w_ih_mu, const float* __restrict__ w_ih_rho,
    const float* __restrict__ w_hh_mu, const float* __restrict__ w_hh_rho,
    const float* __restrict__ b_mu,    const float* __restrict__ b_rho,
    const float* __restrict__ eps_ih,  const float* __restrict__ eps_hh,
    const float* __restrict__ eps_b,
    const float* __restrict__ lin_w,   const float* __restrict__ lin_b,
    float* __restrict__ out, int n_elem)
{
    const int lane = threadIdx.x & 63;
    const int k    = lane & 15;          // unit index within row (pads: 10..15)
    const int row  = lane >> 4;          // 0..3: row within wave
    const int bA   = blockIdx.x * 8 + row * 2;
    const int bB   = bA + 1;
    const int bAe  = (bA < n_elem) ? bA : (n_elem - 1);
    const int bBe  = (bB < n_elem) ? bB : (n_elem - 1);
    const bool un  = (k < HID);

    // ---- sample weights into registers, pre-permuted + input-pre-scaled ----
    Wreg w;
    w.wih01 = splat2(0.f); w.wih23 = splat2(0.f);
    w.b01 = splat2(0.f);   w.b23 = splat2(0.f);
    const v2f s01 = mk2(NLOG2E, NLOG2E);      // {i, f}
    const v2f s23 = mk2(P2LOG2E, NLOG2E);     // {g, o}
    if (un) {
        const int c0 = k, c1 = HID + k, c2 = 2 * HID + k, c3 = 3 * HID + k;
        w.wih01 = s01 * mk2(samp(w_ih_mu, w_ih_rho, eps_ih, c0), samp(w_ih_mu, w_ih_rho, eps_ih, c1));
        w.wih23 = s23 * mk2(samp(w_ih_mu, w_ih_rho, eps_ih, c2), samp(w_ih_mu, w_ih_rho, eps_ih, c3));
        w.b01   = s01 * mk2(samp(b_mu, b_rho, eps_b, c0), samp(b_mu, b_rho, eps_b, c1));
        w.b23   = s23 * mk2(samp(b_mu, b_rho, eps_b, c2), samp(b_mu, b_rho, eps_b, c3));
    }
#pragma unroll
    for (int r = 0; r < 16; ++r) {
        const int idx = (k - r) & 15;    // source h index delivered by ROTF(r)
        if (un && idx < HID) {
            const int base = idx * 4 * HID;
            w.wsel01[r] = s01 * mk2(samp(w_hh_mu, w_hh_rho, eps_hh, base + k),
                                    samp(w_hh_mu, w_hh_rho, eps_hh, base + HID + k));
            w.wsel23[r] = s23 * mk2(samp(w_hh_mu, w_hh_rho, eps_hh, base + 2 * HID + k),
                                    samp(w_hh_mu, w_hh_rho, eps_hh, base + 3 * HID + k));
        } else {
            w.wsel01[r] = splat2(0.f);
            w.wsel23[r] = splat2(0.f);
        }
    }

    // ---- recurrence: 64 chunks x 4 steps, x prefetched one chunk ahead ----
    float csA = 0.f, hkA = 0.f, csB = 0.f, hkB = 0.f;
    const float4* xvA = (const float4*)(x + (size_t)bAe * T_LEN);
    const float4* xvB = (const float4*)(x + (size_t)bBe * T_LEN);
    float4 xqA = xvA[0], xqB = xvB[0];
    for (int ch = 0; ch < 64; ++ch) {
        const int nx = (ch < 63) ? ch + 1 : 63;
        float4 xnA = xvA[nx];
        float4 xnB = xvB[nx];
        lstm_step2(w, xqA.x, xqB.x, hkA, hkB, csA, csB);
        lstm_step2(w, xqA.y, xqB.y, hkA, hkB, csA, csB);
        lstm_step2(w, xqA.z, xqB.z, hkA, hkB, csA, csB);
        lstm_step2(w, xqA.w, xqB.w, hkA, hkB, csA, csB);
        xqA = xnA; xqB = xnB;
    }

    // ---- linear head: reduce h[k]*lw over the 16-lane row (off-loop) ----
    const float lw = un ? lin_w[k] : 0.f;
    float pa = hkA * lw;                 // pad lanes contribute 0
    float pb = hkB * lw;
    pa += __shfl_xor(pa, 1, 16);  pb += __shfl_xor(pb, 1, 16);
    pa += __shfl_xor(pa, 2, 16);  pb += __shfl_xor(pb, 2, 16);
    pa += __shfl_xor(pa, 4, 16);  pb += __shfl_xor(pb, 4, 16);
    pa += __shfl_xor(pa, 8, 16);  pb += __shfl_xor(pb, 8, 16);
    if (k == 0) {
        float b0 = lin_b[0];
        if (bA < n_elem) out[bA] = pa + b0;
        if (bB < n_elem) out[bB] = pb + b0;
    }
}

extern "C" void kernel_launch(void* const* d_in, const int* in_sizes, int n_in,
                              void* d_out, int out_size, void* d_ws, size_t ws_size,
                              hipStream_t stream) {
    const float* x        = (const float*)d_in[0];
    const float* w_ih_mu  = (const float*)d_in[1];
    const float* w_ih_rho = (const float*)d_in[2];
    const float* w_hh_mu  = (const float*)d_in[3];
    const float* w_hh_rho = (const float*)d_in[4];
    const float* b_mu     = (const float*)d_in[5];
    const float* b_rho    = (const float*)d_in[6];
    const float* eps_ih   = (const float*)d_in[7];
    const float* eps_hh   = (const float*)d_in[8];
    const float* eps_b    = (const float*)d_in[9];
    const float* lin_w    = (const float*)d_in[10];
    const float* lin_b    = (const float*)d_in[11];
    float* out = (float*)d_out;

    const int n_b = in_sizes[0] / T_LEN;     // 8192
    dim3 grid((n_b + 7) / 8), block(64);     // 1 wave/block, 8 elements/wave
    hipLaunchKernelGGL(bayes_lstm_kernel, grid, block, 0, stream,
                       x, w_ih_mu, w_ih_rho, w_hh_mu, w_hh_rho, b_mu, b_rho,
                       eps_ih, eps_hh, eps_b, lin_w, lin_b, out, n_b);
}

// Round 8
// 162.794 us; speedup vs baseline: 1.0735x; 1.0735x over previous
//
#include <hip/hip_runtime.h>
#include <math.h>

#define T_LEN 256
#define HID 10

typedef float v2f __attribute__((ext_vector_type(2)));

__device__ __forceinline__ v2f mk2(float a, float b) { v2f r; r.x = a; r.y = b; return r; }
__device__ __forceinline__ v2f splat2(float a) { return mk2(a, a); }

// setup-only accurate softplus
__device__ __forceinline__ float softplus_f(float x) {
    return fmaxf(x, 0.0f) + log1pf(expf(-fabsf(x)));
}
__device__ __forceinline__ float samp(const float* mu, const float* rho,
                                      const float* eps, int i) {
    return mu[i] + softplus_f(rho[i]) * eps[i];
}

#define NLOG2E (-1.442695040888963f)   // i,f,o gate-input pre-scale
#define P2LOG2E (2.885390081777927f)   // g gate-input pre-scale (and c-state scale)

// gate activations on PRE-SCALED inputs (scale folded into weights):
__device__ __forceinline__ float sig_pre(float a) {
    return __builtin_amdgcn_rcpf(1.0f + __builtin_amdgcn_exp2f(a));
}
// g-gate tanh with OUTPUT scaled by P2LOG2E (c kept as cs = P2LOG2E*c)
__device__ __forceinline__ float g_act_scaled(float a) {
    return fmaf(-2.0f * P2LOG2E,
                __builtin_amdgcn_rcpf(__builtin_amdgcn_exp2f(a) + 1.0f),
                P2LOG2E);
}
// tanh(c) from pre-scaled state cs = 2log2e*c
__device__ __forceinline__ float tanh_from_cs(float cs) {
    return fmaf(-2.0f, __builtin_amdgcn_rcpf(__builtin_amdgcn_exp2f(cs) + 1.0f), 1.0f);
}

struct Wreg {
    v2f whh01[HID], whh23[HID];   // recurrent cols {i,f} / {g,o}, pre-scaled
    v2f wih01, wih23, b01, b23;   // pre-scaled
};

// one LSTM step; h in 3 float4s (h[0..9] + 2 ignored pads). 4-deep FMA tree.
__device__ __forceinline__ float lstm_step(const Wreg& w, float xt,
                                           float4 h0, float4 h1, float4 h2,
                                           float& cs)
{
    v2f x2 = splat2(xt);
    v2f A1 = __builtin_elementwise_fma(x2, w.wih01, w.b01);
    v2f A3 = __builtin_elementwise_fma(x2, w.wih23, w.b23);
    A1 = __builtin_elementwise_fma(splat2(h0.x), w.whh01[0], A1);
    A3 = __builtin_elementwise_fma(splat2(h0.x), w.whh23[0], A3);
    v2f B1 = w.whh01[2] * splat2(h0.z);
    v2f B3 = w.whh23[2] * splat2(h0.z);
    v2f C1 = w.whh01[1] * splat2(h0.y);
    v2f C3 = w.whh23[1] * splat2(h0.y);
    v2f D1 = w.whh01[3] * splat2(h0.w);
    v2f D3 = w.whh23[3] * splat2(h0.w);
    A1 = __builtin_elementwise_fma(splat2(h1.x), w.whh01[4], A1);
    A3 = __builtin_elementwise_fma(splat2(h1.x), w.whh23[4], A3);
    B1 = __builtin_elementwise_fma(splat2(h1.z), w.whh01[6], B1);
    B3 = __builtin_elementwise_fma(splat2(h1.z), w.whh23[6], B3);
    C1 = __builtin_elementwise_fma(splat2(h1.y), w.whh01[5], C1);
    C3 = __builtin_elementwise_fma(splat2(h1.y), w.whh23[5], C3);
    D1 = __builtin_elementwise_fma(splat2(h1.w), w.whh01[7], D1);
    D3 = __builtin_elementwise_fma(splat2(h1.w), w.whh23[7], D3);
    A1 = __builtin_elementwise_fma(splat2(h2.x), w.whh01[8], A1);
    A3 = __builtin_elementwise_fma(splat2(h2.x), w.whh23[8], A3);
    C1 = __builtin_elementwise_fma(splat2(h2.y), w.whh01[9], C1);
    C3 = __builtin_elementwise_fma(splat2(h2.y), w.whh23[9], C3);
    v2f a01 = (A1 + B1) + (C1 + D1);
    v2f a23 = (A3 + B3) + (C3 + D3);
    float ig = sig_pre(a01.x);
    float fg = sig_pre(a01.y);
    float gg = g_act_scaled(a23.x);
    float og = sig_pre(a23.y);
    cs = fmaf(fg, cs, ig * gg);          // cs = P2LOG2E * c
    return og * tanh_from_cs(cs);
}

// One wave per block; 4 slots of 16 lanes, 2 element-streams (A,B) per slot ->
// 8 elements/wave, 1024 single-wave blocks = exactly 1 wave per SIMD (densest
// packing). KEY: step t's LDS h-reads for t+1 are issued right after t's
// write, and the OTHER stream's ~230cy of VALU covers the DS round-trip, so
// the read latency that capped R0/R1/R5 at ~390ns/step is hidden.
// Slot layout stride 40 floats (A at +0, B at +20): the 8 b128 broadcast
// reads hit 8 disjoint bank quads; writes are <=2-way (free).
__global__ __launch_bounds__(64) void bayes_lstm_kernel(
    const float* __restrict__ x,
    const float* __restrict__ w_ih_mu, const float* __restrict__ w_ih_rho,
    const float* __restrict__ w_hh_mu, const float* __restrict__ w_hh_rho,
    const float* __restrict__ b_mu,    const float* __restrict__ b_rho,
    const float* __restrict__ eps_ih,  const float* __restrict__ eps_hh,
    const float* __restrict__ eps_b,
    const float* __restrict__ lin_w,   const float* __restrict__ lin_b,
    float* __restrict__ out, int n_elem)
{
    __shared__ __align__(16) float hbuf[4 * 40];

    const int lane = threadIdx.x & 63;
    const int k    = lane & 15;          // unit index (active k < 10)
    const int slot = lane >> 4;          // 0..3
    const int bA   = blockIdx.x * 8 + slot * 2;
    const int bB   = bA + 1;
    const int bAe  = (bA < n_elem) ? bA : (n_elem - 1);
    const int bBe  = (bB < n_elem) ? bB : (n_elem - 1);
    const bool un  = (k < HID);
    float* hbA = hbuf + slot * 40;
    float* hbB = hbuf + slot * 40 + 20;

    // ---- sample weights into registers, PRE-SCALED (k<10 lanes only) ----
    Wreg w;
    w.wih01 = splat2(0.f); w.wih23 = splat2(0.f);
    w.b01 = splat2(0.f);   w.b23 = splat2(0.f);
#pragma unroll
    for (int j = 0; j < HID; ++j) { w.whh01[j] = splat2(0.f); w.whh23[j] = splat2(0.f); }
    const v2f s01 = mk2(NLOG2E, NLOG2E);      // {i, f}
    const v2f s23 = mk2(P2LOG2E, NLOG2E);     // {g, o}
    if (un) {
        const int c0 = k, c1 = HID + k, c2 = 2 * HID + k, c3 = 3 * HID + k;
        w.wih01 = s01 * mk2(samp(w_ih_mu, w_ih_rho, eps_ih, c0), samp(w_ih_mu, w_ih_rho, eps_ih, c1));
        w.wih23 = s23 * mk2(samp(w_ih_mu, w_ih_rho, eps_ih, c2), samp(w_ih_mu, w_ih_rho, eps_ih, c3));
        w.b01   = s01 * mk2(samp(b_mu, b_rho, eps_b, c0), samp(b_mu, b_rho, eps_b, c1));
        w.b23   = s23 * mk2(samp(b_mu, b_rho, eps_b, c2), samp(b_mu, b_rho, eps_b, c3));
#pragma unroll
        for (int j = 0; j < HID; ++j) {
            w.whh01[j] = s01 * mk2(samp(w_hh_mu, w_hh_rho, eps_hh, j * 4 * HID + c0),
                                   samp(w_hh_mu, w_hh_rho, eps_hh, j * 4 * HID + c1));
            w.whh23[j] = s23 * mk2(samp(w_hh_mu, w_hh_rho, eps_hh, j * 4 * HID + c2),
                                   samp(w_hh_mu, w_hh_rho, eps_hh, j * 4 * HID + c3));
        }
    }

    // ---- recurrence ----
    float csA = 0.f, csB = 0.f, hkA = 0.f, hkB = 0.f;
    float4 z = make_float4(0.f, 0.f, 0.f, 0.f);
    float4 hA0 = z, hA1 = z, hA2 = z, hB0 = z, hB1 = z, hB2 = z;
    const float4* pA = (const float4*)hbA;
    const float4* pB = (const float4*)hbB;
    const float4* xvA = (const float4*)(x + (size_t)bAe * T_LEN);
    const float4* xvB = (const float4*)(x + (size_t)bBe * T_LEN);
    float4 xqA = xvA[0], xqB = xvB[0];

    for (int ch = 0; ch < 64; ++ch) {    // 64 chunks x 4 steps = 256
        const int nx = (ch < 63) ? ch + 1 : 63;
        float4 xnA = xvA[nx];            // prefetch next chunk
        float4 xnB = xvB[nx];
#pragma unroll
        for (int ti = 0; ti < 4; ++ti) {
            float xA = (ti == 0) ? xqA.x : (ti == 1) ? xqA.y : (ti == 2) ? xqA.z : xqA.w;
            float xB = (ti == 0) ? xqB.x : (ti == 1) ? xqB.y : (ti == 2) ? xqB.z : xqB.w;
            hkA = lstm_step(w, xA, hA0, hA1, hA2, csA);
            hbA[k] = hkA;                            // write A(t)
            float4 nA0 = pA[0], nA1 = pA[1], nA2 = pA[2];   // issue reads A(t+1)
            hkB = lstm_step(w, xB, hB0, hB1, hB2, csB);     // covers A-read latency
            hbB[k] = hkB;                            // write B(t)
            float4 nB0 = pB[0], nB1 = pB[1], nB2 = pB[2];   // issue reads B(t+1)
            hA0 = nA0; hA1 = nA1; hA2 = nA2;         // (next A covers B-read)
            hB0 = nB0; hB1 = nB1; hB2 = nB2;
        }
        xqA = xnA; xqB = xnB;
    }

    // ---- linear head: reduce h[k]*lw over each 16-lane slot ----
    const float lw = un ? lin_w[k] : 0.f;
    float pa = hkA * lw;                 // lanes k>=10 contribute 0
    float pb = hkB * lw;
    pa += __shfl_xor(pa, 1, 16);  pb += __shfl_xor(pb, 1, 16);
    pa += __shfl_xor(pa, 2, 16);  pb += __shfl_xor(pb, 2, 16);
    pa += __shfl_xor(pa, 4, 16);  pb += __shfl_xor(pb, 4, 16);
    pa += __shfl_xor(pa, 8, 16);  pb += __shfl_xor(pb, 8, 16);
    if (k == 0) {
        float b0 = lin_b[0];
        if (bA < n_elem) out[bA] = pa + b0;
        if (bB < n_elem) out[bB] = pb + b0;
    }
}

extern "C" void kernel_launch(void* const* d_in, const int* in_sizes, int n_in,
                              void* d_out, int out_size, void* d_ws, size_t ws_size,
                              hipStream_t stream) {
    const float* x        = (const float*)d_in[0];
    const float* w_ih_mu  = (const float*)d_in[1];
    const float* w_ih_rho = (const float*)d_in[2];
    const float* w_hh_mu  = (const float*)d_in[3];
    const float* w_hh_rho = (const float*)d_in[4];
    const float* b_mu     = (const float*)d_in[5];
    const float* b_rho    = (const float*)d_in[6];
    const float* eps_ih   = (const float*)d_in[7];
    const float* eps_hh   = (const float*)d_in[8];
    const float* eps_b    = (const float*)d_in[9];
    const float* lin_w    = (const float*)d_in[10];
    const float* lin_b    = (const float*)d_in[11];
    float* out = (float*)d_out;

    const int n_b = in_sizes[0] / T_LEN;     // 8192
    dim3 grid((n_b + 7) / 8), block(64);     // 1 wave/block, 8 elements/wave
    hipLaunchKernelGGL(bayes_lstm_kernel, grid, block, 0, stream,
                       x, w_ih_mu, w_ih_rho, w_hh_mu, w_hh_rho, b_mu, b_rho,
                       eps_ih, eps_hh, eps_b, lin_w, lin_b, out, n_b);
}